// Round 1
// baseline (1176.558 us; speedup 1.0000x reference)
//
#include <hip/hip_runtime.h>
#include <math.h>

#define N_NODES 50000
#define M_FEAT 128
#define E_EDGES 800000
#define B_PAIRS 100000
#define W_RPC 7
#define W_GC 9

// ---------------- utility kernels ----------------

__global__ void k_copy4(const float* __restrict__ in, float* __restrict__ out, int n4) {
    int i = blockIdx.x * blockDim.x + threadIdx.x;
    if (i < n4)
        reinterpret_cast<float4*>(out)[i] = reinterpret_cast<const float4*>(in)[i];
}

__global__ void k_zero(float* __restrict__ buf, int n) {
    int i = blockIdx.x * blockDim.x + threadIdx.x;
    if (i < n) buf[i] = 0.f;
}

__global__ void k_deg(const int* __restrict__ edges, float* __restrict__ deg) {
    int e = blockIdx.x * blockDim.x + threadIdx.x;
    if (e < E_EDGES) atomicAdd(&deg[edges[2 * e + 1]], 1.0f);
}

// ---------------- per-node projection: p[n]=score[n]@w1[:128], q[n]=score[n]@w1[128:] ----------------
// one wave (64 lanes) per node; each lane covers score elements lane and lane+64.

template <int W>
__global__ void k_proj(const float* __restrict__ score, const float* __restrict__ w1,
                       float* __restrict__ p, float* __restrict__ q,
                       float* __restrict__ Hzero) {
    int wave = threadIdx.x >> 6;
    int lane = threadIdx.x & 63;
    int n = blockIdx.x * 4 + wave;
    if (n >= N_NODES) return;
    const float* srow = score + n * M_FEAT;
    float s0 = srow[lane];
    float s1 = srow[lane + 64];
    const float* w1a = w1 + lane * W;           // rows [0,64)
    const float* w1b = w1 + (lane + 64) * W;    // rows [64,128)
    const float* w1c = w1 + (lane + 128) * W;   // rows [128,192)
    const float* w1d = w1 + (lane + 192) * W;   // rows [192,256)
    float pp[W], qq[W];
#pragma unroll
    for (int k = 0; k < W; ++k) {
        pp[k] = s0 * w1a[k] + s1 * w1b[k];
        qq[k] = s0 * w1c[k] + s1 * w1d[k];
    }
#pragma unroll
    for (int off = 32; off > 0; off >>= 1) {
#pragma unroll
        for (int k = 0; k < W; ++k) {
            pp[k] += __shfl_down(pp[k], off);
            qq[k] += __shfl_down(qq[k], off);
        }
    }
    if (lane == 0) {
#pragma unroll
        for (int k = 0; k < W; ++k) {
            p[n * W + k] = pp[k];
            q[n * W + k] = qq[k];
            if (Hzero) Hzero[n * W + k] = 0.f;
        }
    }
}

// ---------------- per-edge MLP, accumulate 7-dim h2 into H[dst] ----------------

__global__ void k_edge(const int* __restrict__ edges, const float* __restrict__ p,
                       const float* __restrict__ q, const float* __restrict__ w2,
                       const float* __restrict__ b1, const float* __restrict__ b2,
                       float* __restrict__ H) {
    int e = blockIdx.x * blockDim.x + threadIdx.x;
    if (e >= E_EDGES) return;
    int src = edges[2 * e];
    int dst = edges[2 * e + 1];
    float h1[W_RPC];
#pragma unroll
    for (int k = 0; k < W_RPC; ++k) {
        float v = p[src * W_RPC + k] + q[dst * W_RPC + k] + b1[k];
        h1[k] = fmaxf(v, 0.f);
    }
#pragma unroll
    for (int j = 0; j < W_RPC; ++j) {
        float v = b2[j];
#pragma unroll
        for (int k = 0; k < W_RPC; ++k) v = fmaf(h1[k], w2[k * W_RPC + j], v);
        atomicAdd(&H[dst * W_RPC + j], fmaxf(v, 0.f));
    }
}

// ---------------- per-node expansion: score[n] += H[n] @ w3 + deg[n]*b3 ----------------

__global__ void k_update(float* __restrict__ score, const float* __restrict__ H,
                         const float* __restrict__ w3, const float* __restrict__ b3,
                         const float* __restrict__ deg) {
    int idx = blockIdx.x * blockDim.x + threadIdx.x;
    if (idx >= N_NODES * M_FEAT) return;
    int n = idx >> 7;
    int m = idx & 127;
    float acc = deg[n] * b3[m];
#pragma unroll
    for (int k = 0; k < W_RPC; ++k)
        acc = fmaf(H[n * W_RPC + k], w3[k * M_FEAT + m], acc);
    score[idx] += acc;
}

// ---------------- final pair scorer ----------------

__global__ void k_pair(const int* __restrict__ lab, const float* __restrict__ r,
                       const float* __restrict__ s, const float* __restrict__ w2,
                       const float* __restrict__ b1, const float* __restrict__ b2,
                       const float* __restrict__ w3, const float* __restrict__ b3,
                       float* __restrict__ out) {
    int b = blockIdx.x * blockDim.x + threadIdx.x;
    if (b >= B_PAIRS) return;
    int a0 = lab[2 * b];
    int a1 = lab[2 * b + 1];
    float g1[W_GC];
#pragma unroll
    for (int k = 0; k < W_GC; ++k) {
        float v = r[a0 * W_GC + k] + s[a1 * W_GC + k] + b1[k];
        g1[k] = fmaxf(v, 0.f);
    }
    float logit = b3[0];
#pragma unroll
    for (int j = 0; j < W_GC; ++j) {
        float v = b2[j];
#pragma unroll
        for (int k = 0; k < W_GC; ++k) v = fmaf(g1[k], w2[k * W_GC + j], v);
        logit = fmaf(fmaxf(v, 0.f), w3[j], logit);
    }
    out[b] = 1.f / (1.f + expf(-logit));
}

// ---------------- launch ----------------

extern "C" void kernel_launch(void* const* d_in, const int* in_sizes, int n_in,
                              void* d_out, int out_size, void* d_ws, size_t ws_size,
                              hipStream_t stream) {
    const float* score_in = (const float*)d_in[0];
    const int*   edges    = (const int*)d_in[1];
    const int*   lab      = (const int*)d_in[2];
    const float* rp_w1 = (const float*)d_in[3];
    const float* rp_b1 = (const float*)d_in[4];
    const float* rp_w2 = (const float*)d_in[5];
    const float* rp_b2 = (const float*)d_in[6];
    const float* rp_w3 = (const float*)d_in[7];
    const float* rp_b3 = (const float*)d_in[8];
    const float* g_w1  = (const float*)d_in[9];
    const float* g_b1  = (const float*)d_in[10];
    const float* g_w2  = (const float*)d_in[11];
    const float* g_b2  = (const float*)d_in[12];
    const float* g_w3  = (const float*)d_in[13];
    const float* g_b3  = (const float*)d_in[14];
    float* out = (float*)d_out;

    // workspace layout (floats): 8.4M floats = 33.6 MB total
    float* ws    = (float*)d_ws;
    float* score = ws;                         // N*M   = 6,400,000
    float* p     = score + N_NODES * M_FEAT;   // N*7   =   350,000
    float* q     = p + N_NODES * W_RPC;        // N*7
    float* H     = q + N_NODES * W_RPC;        // N*7
    float* deg   = H + N_NODES * W_RPC;        // N     =    50,000
    float* r     = deg + N_NODES;              // N*9   =   450,000
    float* s     = r + N_NODES * W_GC;         // N*9

    // init: copy score (don't mutate input), zero+count degrees
    k_copy4<<<(N_NODES * M_FEAT / 4 + 255) / 256, 256, 0, stream>>>(score_in, score, N_NODES * M_FEAT / 4);
    k_zero<<<(N_NODES + 255) / 256, 256, 0, stream>>>(deg, N_NODES);
    k_deg<<<(E_EDGES + 255) / 256, 256, 0, stream>>>(edges, deg);

    for (int t = 0; t < 3; ++t) {
        k_proj<W_RPC><<<(N_NODES + 3) / 4, 256, 0, stream>>>(score, rp_w1, p, q, H);
        k_edge<<<(E_EDGES + 255) / 256, 256, 0, stream>>>(edges, p, q, rp_w2, rp_b1, rp_b2, H);
        k_update<<<(N_NODES * M_FEAT + 255) / 256, 256, 0, stream>>>(score, H, rp_w3, rp_b3, deg);
    }

    k_proj<W_GC><<<(N_NODES + 3) / 4, 256, 0, stream>>>(score, g_w1, r, s, nullptr);
    k_pair<<<(B_PAIRS + 255) / 256, 256, 0, stream>>>(lab, r, s, g_w2, g_b1, g_b2, g_w3, g_b3, out);
}

// Round 2
// 405.771 us; speedup vs baseline: 2.8996x; 2.8996x over previous
//
#include <hip/hip_runtime.h>
#include <math.h>

#define N_NODES 50000
#define M_FEAT 128
#define E_EDGES 800000
#define B_PAIRS 100000
#define W_RPC 7
#define W_GC 9
#define PRP 8              // padded stride for p/q/H (float4-aligned gathers)
#define PG 12              // padded stride for r/s
#define SCAN_B 256
#define NB_SCAN ((N_NODES + SCAN_B - 1) / SCAN_B)   // 196

// ---------------- utility kernels ----------------

__global__ void k_copy4(const float* __restrict__ in, float* __restrict__ out, int n4) {
    int i = blockIdx.x * blockDim.x + threadIdx.x;
    if (i < n4)
        reinterpret_cast<float4*>(out)[i] = reinterpret_cast<const float4*>(in)[i];
}

__global__ void k_zero_int(int* __restrict__ buf, int n) {
    int i = blockIdx.x * blockDim.x + threadIdx.x;
    if (i < n) buf[i] = 0;
}

__global__ void k_deg_int(const int* __restrict__ edges, int* __restrict__ deg) {
    int e = blockIdx.x * blockDim.x + threadIdx.x;
    if (e < E_EDGES) atomicAdd(&deg[edges[2 * e + 1]], 1);
}

// ---------------- exclusive scan over degrees (3-kernel hierarchical) ----------------

__global__ void k_scan1(const int* __restrict__ deg, int* __restrict__ part, int* __restrict__ bsum) {
    __shared__ int sh[SCAN_B];
    int tid = threadIdx.x;
    int i = blockIdx.x * SCAN_B + tid;
    int v = (i < N_NODES) ? deg[i] : 0;
    sh[tid] = v;
    __syncthreads();
    for (int off = 1; off < SCAN_B; off <<= 1) {
        int t = (tid >= off) ? sh[tid - off] : 0;
        __syncthreads();
        sh[tid] += t;
        __syncthreads();
    }
    if (i < N_NODES) part[i] = sh[tid] - v;      // exclusive within block
    if (tid == SCAN_B - 1) bsum[blockIdx.x] = sh[SCAN_B - 1];
}

__global__ void k_scan2(const int* __restrict__ bsum, int* __restrict__ boff) {
    __shared__ int sh[SCAN_B];
    int tid = threadIdx.x;
    int v = (tid < NB_SCAN) ? bsum[tid] : 0;
    sh[tid] = v;
    __syncthreads();
    for (int off = 1; off < SCAN_B; off <<= 1) {
        int t = (tid >= off) ? sh[tid - off] : 0;
        __syncthreads();
        sh[tid] += t;
        __syncthreads();
    }
    if (tid < NB_SCAN) boff[tid] = sh[tid] - v;  // exclusive across blocks
}

__global__ void k_scan3(const int* __restrict__ part, const int* __restrict__ boff,
                        int* __restrict__ off) {
    int i = blockIdx.x * blockDim.x + threadIdx.x;
    if (i < N_NODES) off[i] = part[i] + boff[i >> 8];
    if (i == 0) off[N_NODES] = E_EDGES;
}

// ---------------- scatter edges into dst-sorted order ----------------

__global__ void k_scatter(const int* __restrict__ edges, const int* __restrict__ off,
                          int* __restrict__ cursor, int* __restrict__ srcSorted) {
    int e = blockIdx.x * blockDim.x + threadIdx.x;
    if (e >= E_EDGES) return;
    int src = edges[2 * e];
    int dst = edges[2 * e + 1];
    int pos = off[dst] + atomicAdd(&cursor[dst], 1);
    srcSorted[pos] = src;
}

// ---------------- per-node projection: p[n]=score[n]@w1[:128], q[n]=score[n]@w1[128:] ----------------

template <int W, int PW>
__global__ void k_proj(const float* __restrict__ score, const float* __restrict__ w1,
                       float* __restrict__ p, float* __restrict__ q) {
    int wave = threadIdx.x >> 6;
    int lane = threadIdx.x & 63;
    int n = blockIdx.x * 4 + wave;
    if (n >= N_NODES) return;
    const float* srow = score + n * M_FEAT;
    float s0 = srow[lane];
    float s1 = srow[lane + 64];
    const float* w1a = w1 + lane * W;
    const float* w1b = w1 + (lane + 64) * W;
    const float* w1c = w1 + (lane + 128) * W;
    const float* w1d = w1 + (lane + 192) * W;
    float pp[W], qq[W];
#pragma unroll
    for (int k = 0; k < W; ++k) {
        pp[k] = s0 * w1a[k] + s1 * w1b[k];
        qq[k] = s0 * w1c[k] + s1 * w1d[k];
    }
#pragma unroll
    for (int off = 32; off > 0; off >>= 1) {
#pragma unroll
        for (int k = 0; k < W; ++k) {
            pp[k] += __shfl_down(pp[k], off);
            qq[k] += __shfl_down(qq[k], off);
        }
    }
    if (lane == 0) {
#pragma unroll
        for (int k = 0; k < W; ++k) {
            p[n * PW + k] = pp[k];
            q[n * PW + k] = qq[k];
        }
    }
}

// ---------------- edge MLP, one thread per dst node, no atomics ----------------

__global__ void k_edge_node(const int* __restrict__ srcSorted, const int* __restrict__ off,
                            const float* __restrict__ p, const float* __restrict__ q,
                            const float* __restrict__ w2, const float* __restrict__ b1,
                            const float* __restrict__ b2, float* __restrict__ H) {
    int n = blockIdx.x * blockDim.x + threadIdx.x;
    if (n >= N_NODES) return;
    float w2r[W_RPC * W_RPC], b1r[W_RPC], b2r[W_RPC], qr[W_RPC], acc[W_RPC];
#pragma unroll
    for (int i = 0; i < W_RPC * W_RPC; ++i) w2r[i] = w2[i];   // uniform -> SGPR
#pragma unroll
    for (int k = 0; k < W_RPC; ++k) {
        b1r[k] = b1[k];
        b2r[k] = b2[k];
        qr[k]  = q[n * PRP + k] + b1[k];   // fold b1 into q
        acc[k] = 0.f;
    }
    int s0 = off[n], s1 = off[n + 1];
    if (s0 < s1) {
        int src = srcSorted[s0];
        float4 pa = *reinterpret_cast<const float4*>(p + src * PRP);
        float4 pb = *reinterpret_cast<const float4*>(p + src * PRP + 4);
        for (int pos = s0; pos < s1; ++pos) {
            float4 ca = pa, cb = pb;
            int nxt = pos + 1;
            if (nxt < s1) {                 // 1-deep prefetch of next gather
                int s2 = srcSorted[nxt];
                pa = *reinterpret_cast<const float4*>(p + s2 * PRP);
                pb = *reinterpret_cast<const float4*>(p + s2 * PRP + 4);
            }
            float h1[W_RPC];
            h1[0] = fmaxf(ca.x + qr[0], 0.f);
            h1[1] = fmaxf(ca.y + qr[1], 0.f);
            h1[2] = fmaxf(ca.z + qr[2], 0.f);
            h1[3] = fmaxf(ca.w + qr[3], 0.f);
            h1[4] = fmaxf(cb.x + qr[4], 0.f);
            h1[5] = fmaxf(cb.y + qr[5], 0.f);
            h1[6] = fmaxf(cb.z + qr[6], 0.f);
#pragma unroll
            for (int j = 0; j < W_RPC; ++j) {
                float v = b2r[j];
#pragma unroll
                for (int k = 0; k < W_RPC; ++k) v = fmaf(h1[k], w2r[k * W_RPC + j], v);
                acc[j] += fmaxf(v, 0.f);
            }
        }
    }
#pragma unroll
    for (int k = 0; k < W_RPC; ++k) H[n * PRP + k] = acc[k];
    (void)b1r;
}

// ---------------- per-node expansion: score[n] += H[n] @ w3 + deg[n]*b3 ----------------

__global__ void k_update(float* __restrict__ score, const float* __restrict__ H,
                         const float* __restrict__ w3, const float* __restrict__ b3,
                         const int* __restrict__ off) {
    int idx = blockIdx.x * blockDim.x + threadIdx.x;
    if (idx >= N_NODES * M_FEAT) return;
    int n = idx >> 7;
    int m = idx & 127;
    float degf = (float)(off[n + 1] - off[n]);
    float acc = degf * b3[m];
#pragma unroll
    for (int k = 0; k < W_RPC; ++k)
        acc = fmaf(H[n * PRP + k], w3[k * M_FEAT + m], acc);
    score[idx] += acc;
}

// ---------------- final pair scorer ----------------

__global__ void k_pair(const int* __restrict__ lab, const float* __restrict__ r,
                       const float* __restrict__ s, const float* __restrict__ w2,
                       const float* __restrict__ b1, const float* __restrict__ b2,
                       const float* __restrict__ w3, const float* __restrict__ b3,
                       float* __restrict__ out) {
    int b = blockIdx.x * blockDim.x + threadIdx.x;
    if (b >= B_PAIRS) return;
    int a0 = lab[2 * b];
    int a1 = lab[2 * b + 1];
    float g1[W_GC];
#pragma unroll
    for (int k = 0; k < W_GC; ++k) {
        float v = r[a0 * PG + k] + s[a1 * PG + k] + b1[k];
        g1[k] = fmaxf(v, 0.f);
    }
    float logit = b3[0];
#pragma unroll
    for (int j = 0; j < W_GC; ++j) {
        float v = b2[j];
#pragma unroll
        for (int k = 0; k < W_GC; ++k) v = fmaf(g1[k], w2[k * W_GC + j], v);
        logit = fmaf(fmaxf(v, 0.f), w3[j], logit);
    }
    out[b] = 1.f / (1.f + expf(-logit));
}

// ---------------- launch ----------------

extern "C" void kernel_launch(void* const* d_in, const int* in_sizes, int n_in,
                              void* d_out, int out_size, void* d_ws, size_t ws_size,
                              hipStream_t stream) {
    const float* score_in = (const float*)d_in[0];
    const int*   edges    = (const int*)d_in[1];
    const int*   lab      = (const int*)d_in[2];
    const float* rp_w1 = (const float*)d_in[3];
    const float* rp_b1 = (const float*)d_in[4];
    const float* rp_w2 = (const float*)d_in[5];
    const float* rp_b2 = (const float*)d_in[6];
    const float* rp_w3 = (const float*)d_in[7];
    const float* rp_b3 = (const float*)d_in[8];
    const float* g_w1  = (const float*)d_in[9];
    const float* g_b1  = (const float*)d_in[10];
    const float* g_w2  = (const float*)d_in[11];
    const float* g_b2  = (const float*)d_in[12];
    const float* g_w3  = (const float*)d_in[13];
    const float* g_b3  = (const float*)d_in[14];
    float* out = (float*)d_out;

    // ---- workspace layout ----
    float* ws    = (float*)d_ws;
    float* score = ws;                          // N*M           = 6,400,000 f
    float* p     = score + N_NODES * M_FEAT;    // N*PRP         =   400,000 f
    float* q     = p + N_NODES * PRP;           // N*PRP
    float* H     = q + N_NODES * PRP;           // N*PRP
    float* fend  = H + N_NODES * PRP;
    // r/s overlay p/q/H after the message-passing loop (they're dead then)
    float* r     = p;                           // N*PG = 600,000 f  (fits in p+q)
    float* s     = p + N_NODES * PG;            // next 600,000 f (ends inside H+pad) -- ensure space:
    // p..fend spans 1,200,000 floats; r+s need 1,200,000 floats exactly. OK.
    int* ib        = (int*)fend;
    int* off       = ib;                        // N+1
    int* cursor    = off + N_NODES + 1;         // N
    int* degI      = cursor + N_NODES;          // N
    int* part      = degI + N_NODES;            // N
    int* bsum      = part + N_NODES;            // 256
    int* boff      = bsum + SCAN_B;             // 256
    int* srcSorted = boff + SCAN_B;             // E

    // ---- preprocessing: copy score; bucket edges by dst ----
    k_copy4<<<(N_NODES * M_FEAT / 4 + 255) / 256, 256, 0, stream>>>(score_in, score, N_NODES * M_FEAT / 4);
    k_zero_int<<<(2 * N_NODES + 255) / 256, 256, 0, stream>>>(cursor, 2 * N_NODES);  // cursor + degI
    k_deg_int<<<(E_EDGES + 255) / 256, 256, 0, stream>>>(edges, degI);
    k_scan1<<<NB_SCAN, SCAN_B, 0, stream>>>(degI, part, bsum);
    k_scan2<<<1, SCAN_B, 0, stream>>>(bsum, boff);
    k_scan3<<<NB_SCAN, SCAN_B, 0, stream>>>(part, boff, off);
    k_scatter<<<(E_EDGES + 255) / 256, 256, 0, stream>>>(edges, off, cursor, srcSorted);

    // ---- 3 rounds of message passing ----
    for (int t = 0; t < 3; ++t) {
        k_proj<W_RPC, PRP><<<(N_NODES + 3) / 4, 256, 0, stream>>>(score, rp_w1, p, q);
        k_edge_node<<<(N_NODES + 255) / 256, 256, 0, stream>>>(srcSorted, off, p, q, rp_w2, rp_b1, rp_b2, H);
        k_update<<<(N_NODES * M_FEAT + 255) / 256, 256, 0, stream>>>(score, H, rp_w3, rp_b3, off);
    }

    // ---- final pair scorer ----
    k_proj<W_GC, PG><<<(N_NODES + 3) / 4, 256, 0, stream>>>(score, g_w1, r, s);
    k_pair<<<(B_PAIRS + 255) / 256, 256, 0, stream>>>(lab, r, s, g_w2, g_b1, g_b2, g_w3, g_b3, out);
}

// Round 3
// 181.011 us; speedup vs baseline: 6.4999x; 2.2417x over previous
//
#include <hip/hip_runtime.h>
#include <math.h>

#define N_NODES 50000
#define M_FEAT 128
#define E_EDGES 800000
#define B_PAIRS 100000
#define PRP 8              // stride for p/q/H/Hsum
#define PG 16              // stride for r/s
#define SCAN_B 256
#define NB_SCAN ((N_NODES + SCAN_B - 1) / SCAN_B)   // 196

// offsets into the small fused-weight buffer Wsm (256 floats)
#define OFF_WPP 0     // 7x7: Wpp[i*7+j] = sum_m w3[i,m] * w1[m, j]        (w1a)
#define OFF_WQQ 49    // 7x7: vs w1[m+128, j]                              (w1b)
#define OFF_WR  98    // 7x9: vs g_w1[m, j]                                (g_w1a)
#define OFF_WS  161   // 7x9: vs g_w1[m+128, j]                            (g_w1b)
#define OFF_BP  224   // 7:   b3 @ w1a
#define OFF_BQ  231   // 7:   b3 @ w1b
#define OFF_BR  238   // 9:   b3 @ g_w1a
#define OFF_BS  247   // 9:   b3 @ g_w1b

// ---------------- sort pipeline ----------------

__global__ void k_zero_int(int* __restrict__ buf, int n) {
    int i = blockIdx.x * blockDim.x + threadIdx.x;
    if (i < n) buf[i] = 0;
}

__global__ void k_deg_int(const int* __restrict__ edges, int* __restrict__ deg) {
    int e = blockIdx.x * blockDim.x + threadIdx.x;
    if (e < E_EDGES) atomicAdd(&deg[edges[2 * e + 1]], 1);
}

__global__ void k_scan1(const int* __restrict__ deg, int* __restrict__ part, int* __restrict__ bsum) {
    __shared__ int sh[SCAN_B];
    int tid = threadIdx.x;
    int i = blockIdx.x * SCAN_B + tid;
    int v = (i < N_NODES) ? deg[i] : 0;
    sh[tid] = v;
    __syncthreads();
    for (int off = 1; off < SCAN_B; off <<= 1) {
        int t = (tid >= off) ? sh[tid - off] : 0;
        __syncthreads();
        sh[tid] += t;
        __syncthreads();
    }
    if (i < N_NODES) part[i] = sh[tid] - v;
    if (tid == SCAN_B - 1) bsum[blockIdx.x] = sh[SCAN_B - 1];
}

__global__ void k_scan2(const int* __restrict__ bsum, int* __restrict__ boff) {
    __shared__ int sh[SCAN_B];
    int tid = threadIdx.x;
    int v = (tid < NB_SCAN) ? bsum[tid] : 0;
    sh[tid] = v;
    __syncthreads();
    for (int off = 1; off < SCAN_B; off <<= 1) {
        int t = (tid >= off) ? sh[tid - off] : 0;
        __syncthreads();
        sh[tid] += t;
        __syncthreads();
    }
    if (tid < NB_SCAN) boff[tid] = sh[tid] - v;
}

__global__ void k_scan3(const int* __restrict__ part, const int* __restrict__ boff,
                        int* __restrict__ off) {
    int i = blockIdx.x * blockDim.x + threadIdx.x;
    if (i < N_NODES) off[i] = part[i] + boff[i >> 8];
    if (i == 0) off[N_NODES] = E_EDGES;
}

__global__ void k_scatter(const int* __restrict__ edges, const int* __restrict__ off,
                          int* __restrict__ cursor, int* __restrict__ srcSorted) {
    int e = blockIdx.x * blockDim.x + threadIdx.x;
    if (e >= E_EDGES) return;
    int src = edges[2 * e];
    int dst = edges[2 * e + 1];
    int pos = off[dst] + atomicAdd(&cursor[dst], 1);
    srcSorted[pos] = src;
}

// ---------------- weight packing ----------------
// Wbig[m][o], m in [0,128), o in [0,32): cols = [p(7) | q(7) | r(9) | s(9)]

__global__ void k_wbig(const float* __restrict__ rp_w1, const float* __restrict__ g_w1,
                       float* __restrict__ Wbig) {
    int t = blockIdx.x * blockDim.x + threadIdx.x;
    if (t >= 128 * 32) return;
    int m = t >> 5, o = t & 31;
    float v;
    if (o < 7)       v = rp_w1[m * 7 + o];
    else if (o < 14) v = rp_w1[(m + 128) * 7 + (o - 7)];
    else if (o < 23) v = g_w1[m * 9 + (o - 14)];
    else             v = g_w1[(m + 128) * 9 + (o - 23)];
    Wbig[m * 32 + o] = v;
}

// fused small weights: Wpp=w3@w1a etc. 256 outputs, one thread each.
__global__ void k_wfuse(const float* __restrict__ w3, const float* __restrict__ b3,
                        const float* __restrict__ rp_w1, const float* __restrict__ g_w1,
                        float* __restrict__ Wsm) {
    int t = threadIdx.x;
    float acc = 0.f;
    if (t < 49) {
        int i = t / 7, j = t % 7;
        for (int m = 0; m < 128; ++m) acc = fmaf(w3[i * 128 + m], rp_w1[m * 7 + j], acc);
    } else if (t < 98) {
        int u = t - 49; int i = u / 7, j = u % 7;
        for (int m = 0; m < 128; ++m) acc = fmaf(w3[i * 128 + m], rp_w1[(m + 128) * 7 + j], acc);
    } else if (t < 161) {
        int u = t - 98; int i = u / 9, j = u % 9;
        for (int m = 0; m < 128; ++m) acc = fmaf(w3[i * 128 + m], g_w1[m * 9 + j], acc);
    } else if (t < 224) {
        int u = t - 161; int i = u / 9, j = u % 9;
        for (int m = 0; m < 128; ++m) acc = fmaf(w3[i * 128 + m], g_w1[(m + 128) * 9 + j], acc);
    } else if (t < 231) {
        int j = t - 224;
        for (int m = 0; m < 128; ++m) acc = fmaf(b3[m], rp_w1[m * 7 + j], acc);
    } else if (t < 238) {
        int j = t - 231;
        for (int m = 0; m < 128; ++m) acc = fmaf(b3[m], rp_w1[(m + 128) * 7 + j], acc);
    } else if (t < 247) {
        int j = t - 238;
        for (int m = 0; m < 128; ++m) acc = fmaf(b3[m], g_w1[m * 9 + j], acc);
    } else {
        int j = t - 247;
        for (int m = 0; m < 128; ++m) acc = fmaf(b3[m], g_w1[(m + 128) * 9 + j], acc);
    }
    Wsm[t] = acc;
}

// ---------------- fused projection: p,q,r,s = score0 @ Wbig ----------------
// lane = mg*8 + og; mg in [0,8) owns 16 m-values; og in [0,8) owns 4 outputs.
// weights loaded ONCE per wave into 64 VGPRs; grid-stride over nodes.

__global__ void __launch_bounds__(256) k_proj_fused(
        const float* __restrict__ score, const float* __restrict__ Wbig,
        float* __restrict__ p, float* __restrict__ q,
        float* __restrict__ r, float* __restrict__ s, int totalWaves) {
    int gtid = blockIdx.x * 256 + threadIdx.x;
    int wave = gtid >> 6, lane = gtid & 63;
    int mg = lane >> 3, og = lane & 7;

    const float4* wb4 = reinterpret_cast<const float4*>(Wbig);  // [m*8 + o4]
    float4 w[16];
#pragma unroll
    for (int i = 0; i < 16; ++i) w[i] = wb4[(mg * 16 + i) * 8 + og];

    for (int n = wave; n < N_NODES; n += totalWaves) {
        const float4* srow = reinterpret_cast<const float4*>(score + n * M_FEAT + mg * 16);
        float a0 = 0.f, a1 = 0.f, a2 = 0.f, a3 = 0.f;
#pragma unroll
        for (int i = 0; i < 4; ++i) {
            float4 sv = srow[i];
            float se[4] = {sv.x, sv.y, sv.z, sv.w};
#pragma unroll
            for (int e = 0; e < 4; ++e) {
                float4 ww = w[i * 4 + e];
                a0 = fmaf(se[e], ww.x, a0);
                a1 = fmaf(se[e], ww.y, a1);
                a2 = fmaf(se[e], ww.z, a2);
                a3 = fmaf(se[e], ww.w, a3);
            }
        }
#pragma unroll
        for (int off = 32; off >= 8; off >>= 1) {
            a0 += __shfl_down(a0, off);
            a1 += __shfl_down(a1, off);
            a2 += __shfl_down(a2, off);
            a3 += __shfl_down(a3, off);
        }
        if (mg == 0) {
            float outv[4] = {a0, a1, a2, a3};
#pragma unroll
            for (int jj = 0; jj < 4; ++jj) {
                int o = og * 4 + jj;
                float v = outv[jj];
                if (o < 7)       p[n * PRP + o] = v;
                else if (o < 14) q[n * PRP + (o - 7)] = v;
                else if (o < 23) r[n * PG + (o - 14)] = v;
                else             s[n * PG + (o - 23)] = v;
            }
        }
    }
}

// ---------------- edge MLP: 4 lanes per dst node, no atomics ----------------

template <bool FIRST>
__global__ void k_edge_node(const int* __restrict__ srcSorted, const int* __restrict__ off,
                            const float* __restrict__ p, const float* __restrict__ q,
                            const float* __restrict__ w2, const float* __restrict__ b1,
                            const float* __restrict__ b2, float* __restrict__ H,
                            float* __restrict__ Hsum) {
    int gt = blockIdx.x * blockDim.x + threadIdx.x;
    int n = gt >> 2, sub = gt & 3;
    if (n >= N_NODES) return;
    float w2r[49], qr[7], b2r[7], acc[7];
#pragma unroll
    for (int i = 0; i < 49; ++i) w2r[i] = w2[i];   // uniform -> scalar loads
#pragma unroll
    for (int k = 0; k < 7; ++k) {
        qr[k] = q[n * PRP + k] + b1[k];
        b2r[k] = b2[k];
        acc[k] = 0.f;
    }
    int s0 = off[n], s1 = off[n + 1];
    for (int pos = s0 + sub; pos < s1; pos += 4) {
        int src = srcSorted[pos];
        float4 pa = *reinterpret_cast<const float4*>(p + src * PRP);
        float4 pb = *reinterpret_cast<const float4*>(p + src * PRP + 4);
        float h1[7];
        h1[0] = fmaxf(pa.x + qr[0], 0.f);
        h1[1] = fmaxf(pa.y + qr[1], 0.f);
        h1[2] = fmaxf(pa.z + qr[2], 0.f);
        h1[3] = fmaxf(pa.w + qr[3], 0.f);
        h1[4] = fmaxf(pb.x + qr[4], 0.f);
        h1[5] = fmaxf(pb.y + qr[5], 0.f);
        h1[6] = fmaxf(pb.z + qr[6], 0.f);
#pragma unroll
        for (int j = 0; j < 7; ++j) {
            float v = b2r[j];
#pragma unroll
            for (int k = 0; k < 7; ++k) v = fmaf(h1[k], w2r[k * 7 + j], v);
            acc[j] += fmaxf(v, 0.f);
        }
    }
#pragma unroll
    for (int j = 0; j < 7; ++j) {
        acc[j] += __shfl_down(acc[j], 2);
        acc[j] += __shfl_down(acc[j], 1);
    }
    if (sub == 0) {
#pragma unroll
        for (int j = 0; j < 7; ++j) {
            H[n * PRP + j] = acc[j];
            if (FIRST) Hsum[n * PRP + j] = acc[j];
            else       Hsum[n * PRP + j] += acc[j];
        }
    }
}

// ---------------- tiny per-node propagation of the projections ----------------

__global__ void k_small_pq(float* __restrict__ p, float* __restrict__ q,
                           const float* __restrict__ H, const float* __restrict__ Wsm,
                           const int* __restrict__ off) {
    int n = blockIdx.x * blockDim.x + threadIdx.x;
    if (n >= N_NODES) return;
    float h[7];
#pragma unroll
    for (int k = 0; k < 7; ++k) h[k] = H[n * PRP + k];
    float degf = (float)(off[n + 1] - off[n]);
#pragma unroll
    for (int j = 0; j < 7; ++j) {
        float vp = degf * Wsm[OFF_BP + j];
        float vq = degf * Wsm[OFF_BQ + j];
#pragma unroll
        for (int i = 0; i < 7; ++i) {
            vp = fmaf(h[i], Wsm[OFF_WPP + i * 7 + j], vp);
            vq = fmaf(h[i], Wsm[OFF_WQQ + i * 7 + j], vq);
        }
        p[n * PRP + j] += vp;
        q[n * PRP + j] += vq;
    }
}

__global__ void k_small_rs(float* __restrict__ r, float* __restrict__ s,
                           const float* __restrict__ Hsum, const float* __restrict__ Wsm,
                           const int* __restrict__ off) {
    int n = blockIdx.x * blockDim.x + threadIdx.x;
    if (n >= N_NODES) return;
    float h[7];
#pragma unroll
    for (int k = 0; k < 7; ++k) h[k] = Hsum[n * PRP + k];
    float deg3 = 3.f * (float)(off[n + 1] - off[n]);
#pragma unroll
    for (int j = 0; j < 9; ++j) {
        float vr = deg3 * Wsm[OFF_BR + j];
        float vs = deg3 * Wsm[OFF_BS + j];
#pragma unroll
        for (int i = 0; i < 7; ++i) {
            vr = fmaf(h[i], Wsm[OFF_WR + i * 9 + j], vr);
            vs = fmaf(h[i], Wsm[OFF_WS + i * 9 + j], vs);
        }
        r[n * PG + j] += vr;
        s[n * PG + j] += vs;
    }
}

// ---------------- final pair scorer ----------------

__global__ void k_pair(const int* __restrict__ lab, const float* __restrict__ r,
                       const float* __restrict__ s, const float* __restrict__ w2,
                       const float* __restrict__ b1, const float* __restrict__ b2,
                       const float* __restrict__ w3, const float* __restrict__ b3,
                       float* __restrict__ out) {
    int b = blockIdx.x * blockDim.x + threadIdx.x;
    if (b >= B_PAIRS) return;
    int a0 = lab[2 * b];
    int a1 = lab[2 * b + 1];
    const float4* ra = reinterpret_cast<const float4*>(r + a0 * PG);
    const float4* sa = reinterpret_cast<const float4*>(s + a1 * PG);
    float4 r0 = ra[0], r1 = ra[1];
    float4 s0 = sa[0], s1 = sa[1];
    float rv[9] = {r0.x, r0.y, r0.z, r0.w, r1.x, r1.y, r1.z, r1.w, r[a0 * PG + 8]};
    float sv[9] = {s0.x, s0.y, s0.z, s0.w, s1.x, s1.y, s1.z, s1.w, s[a1 * PG + 8]};
    float g1[9];
#pragma unroll
    for (int k = 0; k < 9; ++k) g1[k] = fmaxf(rv[k] + sv[k] + b1[k], 0.f);
    float logit = b3[0];
#pragma unroll
    for (int j = 0; j < 9; ++j) {
        float v = b2[j];
#pragma unroll
        for (int k = 0; k < 9; ++k) v = fmaf(g1[k], w2[k * 9 + j], v);
        logit = fmaf(fmaxf(v, 0.f), w3[j], logit);
    }
    out[b] = 1.f / (1.f + expf(-logit));
}

// ---------------- launch ----------------

extern "C" void kernel_launch(void* const* d_in, const int* in_sizes, int n_in,
                              void* d_out, int out_size, void* d_ws, size_t ws_size,
                              hipStream_t stream) {
    const float* score = (const float*)d_in[0];
    const int*   edges = (const int*)d_in[1];
    const int*   lab   = (const int*)d_in[2];
    const float* rp_w1 = (const float*)d_in[3];
    const float* rp_b1 = (const float*)d_in[4];
    const float* rp_w2 = (const float*)d_in[5];
    const float* rp_b2 = (const float*)d_in[6];
    const float* rp_w3 = (const float*)d_in[7];
    const float* rp_b3 = (const float*)d_in[8];
    const float* g_w1  = (const float*)d_in[9];
    const float* g_b1  = (const float*)d_in[10];
    const float* g_w2  = (const float*)d_in[11];
    const float* g_b2  = (const float*)d_in[12];
    const float* g_w3  = (const float*)d_in[13];
    const float* g_b3  = (const float*)d_in[14];
    float* out = (float*)d_out;

    // ---- workspace layout ----
    float* ws   = (float*)d_ws;
    float* p    = ws;                       // N*8
    float* q    = p + N_NODES * PRP;        // N*8
    float* H    = q + N_NODES * PRP;        // N*8
    float* Hs   = H + N_NODES * PRP;        // N*8
    float* r    = Hs + N_NODES * PRP;       // N*16
    float* s    = r + N_NODES * PG;         // N*16
    float* Wbig = s + N_NODES * PG;         // 4096
    float* Wsm  = Wbig + 4096;              // 256
    int* off       = (int*)(Wsm + 256);     // N+1
    int* cursor    = off + N_NODES + 1;     // N
    int* degI      = cursor + N_NODES;      // N
    int* part      = degI + N_NODES;        // N
    int* bsum      = part + N_NODES;        // 256
    int* boff      = bsum + SCAN_B;         // 256
    int* srcSorted = boff + SCAN_B;         // E

    // ---- sort edges by dst ----
    k_zero_int<<<(2 * N_NODES + 255) / 256, 256, 0, stream>>>(cursor, 2 * N_NODES);  // cursor+degI
    k_deg_int<<<(E_EDGES + 255) / 256, 256, 0, stream>>>(edges, degI);
    k_scan1<<<NB_SCAN, SCAN_B, 0, stream>>>(degI, part, bsum);
    k_scan2<<<1, SCAN_B, 0, stream>>>(bsum, boff);
    k_scan3<<<NB_SCAN, SCAN_B, 0, stream>>>(part, boff, off);
    k_scatter<<<(E_EDGES + 255) / 256, 256, 0, stream>>>(edges, off, cursor, srcSorted);

    // ---- pack weights ----
    k_wbig<<<16, 256, 0, stream>>>(rp_w1, g_w1, Wbig);
    k_wfuse<<<1, 256, 0, stream>>>(rp_w3, rp_b3, rp_w1, g_w1, Wsm);

    // ---- one fused projection of the ORIGINAL score ----
    const int PROJ_BLOCKS = 1280;
    k_proj_fused<<<PROJ_BLOCKS, 256, 0, stream>>>(score, Wbig, p, q, r, s, PROJ_BLOCKS * 4);

    // ---- 3 rounds, all in the tiny projected space ----
    const int EG = (4 * N_NODES + 255) / 256;
    const int NG = (N_NODES + 255) / 256;
    k_edge_node<true><<<EG, 256, 0, stream>>>(srcSorted, off, p, q, rp_w2, rp_b1, rp_b2, H, Hs);
    k_small_pq<<<NG, 256, 0, stream>>>(p, q, H, Wsm, off);
    k_edge_node<false><<<EG, 256, 0, stream>>>(srcSorted, off, p, q, rp_w2, rp_b1, rp_b2, H, Hs);
    k_small_pq<<<NG, 256, 0, stream>>>(p, q, H, Wsm, off);
    k_edge_node<false><<<EG, 256, 0, stream>>>(srcSorted, off, p, q, rp_w2, rp_b1, rp_b2, H, Hs);
    k_small_rs<<<NG, 256, 0, stream>>>(r, s, Hs, Wsm, off);

    // ---- final pair scorer ----
    k_pair<<<(B_PAIRS + 255) / 256, 256, 0, stream>>>(lab, r, s, g_w2, g_b1, g_b2, g_w3, g_b3, out);
}

// Round 4
// 123.867 us; speedup vs baseline: 9.4986x; 1.4613x over previous
//
#include <hip/hip_runtime.h>
#include <math.h>

#define N_NODES 50000
#define M_FEAT 128
#define E_EDGES 800000
#define B_PAIRS 100000
#define PRP 8              // stride for p/q/H/Hsum
#define PG 16              // stride for r/s

#define CH 4096                                  // edges per chunk (pass A)
#define NCHUNK ((E_EDGES + CH - 1) / CH)         // 196
#define NBUCKET ((N_NODES + 255) / 256)          // 196 coarse buckets (dst>>8)
#define HSZ (NBUCKET * NCHUNK)                   // 38416

// offsets into the small fused-weight buffer Wsm (256 floats)
#define OFF_WPP 0
#define OFF_WQQ 49
#define OFF_WR  98
#define OFF_WS  161
#define OFF_BP  224
#define OFF_BQ  231
#define OFF_BR  238
#define OFF_BS  247

// ---------------- pass A: coarse-bucket histogram ----------------

__global__ void k_histA(const int2* __restrict__ edges, int* __restrict__ histT) {
    __shared__ int cnt[NBUCKET];
    int c = blockIdx.x;
    int tid = threadIdx.x;
    if (tid < NBUCKET) cnt[tid] = 0;
    __syncthreads();
    int base = c * CH;
#pragma unroll
    for (int k = 0; k < CH / 256; ++k) {
        int i = base + k * 256 + tid;
        if (i < E_EDGES) atomicAdd(&cnt[edges[i].y >> 8], 1);
    }
    __syncthreads();
    if (tid < NBUCKET) histT[tid * NCHUNK + c] = cnt[tid];   // bucket-major
}

// ---------------- generalized hierarchical exclusive scan ----------------

__global__ void k_scan1(const int* __restrict__ in, int* __restrict__ part,
                        int* __restrict__ bsum, int n) {
    __shared__ int sh[256];
    int tid = threadIdx.x;
    int i = blockIdx.x * 256 + tid;
    int v = (i < n) ? in[i] : 0;
    sh[tid] = v;
    __syncthreads();
    for (int off = 1; off < 256; off <<= 1) {
        int t = (tid >= off) ? sh[tid - off] : 0;
        __syncthreads();
        sh[tid] += t;
        __syncthreads();
    }
    if (i < n) part[i] = sh[tid] - v;
    if (tid == 255) bsum[blockIdx.x] = sh[255];
}

__global__ void k_scan2(const int* __restrict__ bsum, int* __restrict__ boff, int nb) {
    __shared__ int sh[256];
    int tid = threadIdx.x;
    int v = (tid < nb) ? bsum[tid] : 0;
    sh[tid] = v;
    __syncthreads();
    for (int off = 1; off < 256; off <<= 1) {
        int t = (tid >= off) ? sh[tid - off] : 0;
        __syncthreads();
        sh[tid] += t;
        __syncthreads();
    }
    if (tid < nb) boff[tid] = sh[tid] - v;
}

__global__ void k_scan3(const int* __restrict__ part, const int* __restrict__ boff,
                        int* __restrict__ out, int n) {
    int i = blockIdx.x * blockDim.x + threadIdx.x;
    if (i < n) out[i] = part[i] + boff[i >> 8];
}

// ---------------- pass A scatter: group edges by coarse bucket ----------------

__global__ void k_scatterA(const int2* __restrict__ edges, const int* __restrict__ histTs,
                           int2* __restrict__ bucketed) {
    __shared__ int offl[NBUCKET];
    int c = blockIdx.x, tid = threadIdx.x;
    if (tid < NBUCKET) offl[tid] = histTs[tid * NCHUNK + c];
    __syncthreads();
    int base = c * CH;
#pragma unroll
    for (int k = 0; k < CH / 256; ++k) {
        int i = base + k * 256 + tid;
        if (i < E_EDGES) {
            int2 e = edges[i];
            int pos = atomicAdd(&offl[e.y >> 8], 1);
            bucketed[pos] = e;
        }
    }
}

// ---------------- pass B: per-bucket fine sort + CSR offsets ----------------

__global__ void k_passB(const int2* __restrict__ bucketed, const int* __restrict__ histTs,
                        int* __restrict__ srcSorted, int* __restrict__ off) {
    __shared__ int cnt[256], loc[256], cur[256], sh[256];
    int b = blockIdx.x, tid = threadIdx.x;
    int base0 = histTs[b * NCHUNK];
    int base1 = (b + 1 < NBUCKET) ? histTs[(b + 1) * NCHUNK] : E_EDGES;
    int nb = base1 - base0;
    cnt[tid] = 0;
    __syncthreads();
    for (int i = tid; i < nb; i += 256)
        atomicAdd(&cnt[bucketed[base0 + i].y & 255], 1);
    __syncthreads();
    int v = cnt[tid];
    sh[tid] = v;
    __syncthreads();
    for (int o = 1; o < 256; o <<= 1) {
        int t = (tid >= o) ? sh[tid - o] : 0;
        __syncthreads();
        sh[tid] += t;
        __syncthreads();
    }
    loc[tid] = sh[tid] - v;
    cur[tid] = 0;
    __syncthreads();
    int d0 = b * 256;
    if (d0 + tid < N_NODES) off[d0 + tid] = base0 + loc[tid];
    if (b == 0 && tid == 0) off[N_NODES] = E_EDGES;
    for (int i = tid; i < nb; i += 256) {
        int2 e = bucketed[base0 + i];
        int dl = e.y & 255;
        int pos = base0 + loc[dl] + atomicAdd(&cur[dl], 1);
        srcSorted[pos] = e.x;
    }
}

// ---------------- weight packing (Wbig + fused small weights, one dispatch) ----------------

__global__ void k_wpack(const float* __restrict__ rp_w1, const float* __restrict__ g_w1,
                        const float* __restrict__ w3, const float* __restrict__ b3,
                        float* __restrict__ Wbig, float* __restrict__ Wsm) {
    if (blockIdx.x < 16) {
        int t = blockIdx.x * 256 + threadIdx.x;   // 4096 = 128*32
        int m = t >> 5, o = t & 31;
        float v;
        if (o < 7)       v = rp_w1[m * 7 + o];
        else if (o < 14) v = rp_w1[(m + 128) * 7 + (o - 7)];
        else if (o < 23) v = g_w1[m * 9 + (o - 14)];
        else             v = g_w1[(m + 128) * 9 + (o - 23)];
        Wbig[m * 32 + o] = v;
        return;
    }
    int t = threadIdx.x;
    float acc = 0.f;
    if (t < 49) {
        int i = t / 7, j = t % 7;
        for (int m = 0; m < 128; ++m) acc = fmaf(w3[i * 128 + m], rp_w1[m * 7 + j], acc);
    } else if (t < 98) {
        int u = t - 49; int i = u / 7, j = u % 7;
        for (int m = 0; m < 128; ++m) acc = fmaf(w3[i * 128 + m], rp_w1[(m + 128) * 7 + j], acc);
    } else if (t < 161) {
        int u = t - 98; int i = u / 9, j = u % 9;
        for (int m = 0; m < 128; ++m) acc = fmaf(w3[i * 128 + m], g_w1[m * 9 + j], acc);
    } else if (t < 224) {
        int u = t - 161; int i = u / 9, j = u % 9;
        for (int m = 0; m < 128; ++m) acc = fmaf(w3[i * 128 + m], g_w1[(m + 128) * 9 + j], acc);
    } else if (t < 231) {
        int j = t - 224;
        for (int m = 0; m < 128; ++m) acc = fmaf(b3[m], rp_w1[m * 7 + j], acc);
    } else if (t < 238) {
        int j = t - 231;
        for (int m = 0; m < 128; ++m) acc = fmaf(b3[m], rp_w1[(m + 128) * 7 + j], acc);
    } else if (t < 247) {
        int j = t - 238;
        for (int m = 0; m < 128; ++m) acc = fmaf(b3[m], g_w1[m * 9 + j], acc);
    } else {
        int j = t - 247;
        for (int m = 0; m < 128; ++m) acc = fmaf(b3[m], g_w1[(m + 128) * 9 + j], acc);
    }
    Wsm[t] = acc;
}

// ---------------- fused projection: p,q,r,s = score0 @ Wbig ----------------

__global__ void __launch_bounds__(256) k_proj_fused(
        const float* __restrict__ score, const float* __restrict__ Wbig,
        float* __restrict__ p, float* __restrict__ q,
        float* __restrict__ r, float* __restrict__ s, int totalWaves) {
    int gtid = blockIdx.x * 256 + threadIdx.x;
    int wave = gtid >> 6, lane = gtid & 63;
    int mg = lane >> 3, og = lane & 7;

    const float4* wb4 = reinterpret_cast<const float4*>(Wbig);
    float4 w[16];
#pragma unroll
    for (int i = 0; i < 16; ++i) w[i] = wb4[(mg * 16 + i) * 8 + og];

    for (int n = wave; n < N_NODES; n += totalWaves) {
        const float4* srow = reinterpret_cast<const float4*>(score + n * M_FEAT + mg * 16);
        float a0 = 0.f, a1 = 0.f, a2 = 0.f, a3 = 0.f;
#pragma unroll
        for (int i = 0; i < 4; ++i) {
            float4 sv = srow[i];
            float se[4] = {sv.x, sv.y, sv.z, sv.w};
#pragma unroll
            for (int e = 0; e < 4; ++e) {
                float4 ww = w[i * 4 + e];
                a0 = fmaf(se[e], ww.x, a0);
                a1 = fmaf(se[e], ww.y, a1);
                a2 = fmaf(se[e], ww.z, a2);
                a3 = fmaf(se[e], ww.w, a3);
            }
        }
#pragma unroll
        for (int off = 32; off >= 8; off >>= 1) {
            a0 += __shfl_down(a0, off);
            a1 += __shfl_down(a1, off);
            a2 += __shfl_down(a2, off);
            a3 += __shfl_down(a3, off);
        }
        if (mg == 0) {
            float outv[4] = {a0, a1, a2, a3};
#pragma unroll
            for (int jj = 0; jj < 4; ++jj) {
                int o = og * 4 + jj;
                float v = outv[jj];
                if (o < 7)       p[n * PRP + o] = v;
                else if (o < 14) q[n * PRP + (o - 7)] = v;
                else if (o < 23) r[n * PG + (o - 14)] = v;
                else             s[n * PG + (o - 23)] = v;
            }
        }
    }
}

// ---------------- edge MLP: 8 lanes per dst node, no atomics ----------------

template <bool FIRST>
__global__ void k_edge_node(const int* __restrict__ srcSorted, const int* __restrict__ off,
                            const float* __restrict__ p, const float* __restrict__ q,
                            const float* __restrict__ w2, const float* __restrict__ b1,
                            const float* __restrict__ b2, float* __restrict__ H,
                            float* __restrict__ Hsum) {
    int gt = blockIdx.x * blockDim.x + threadIdx.x;
    int n = gt >> 3, sub = gt & 7;
    if (n >= N_NODES) return;
    float w2r[49], qr[7], b2r[7], acc[7];
#pragma unroll
    for (int i = 0; i < 49; ++i) w2r[i] = w2[i];
#pragma unroll
    for (int k = 0; k < 7; ++k) {
        qr[k] = q[n * PRP + k] + b1[k];
        b2r[k] = b2[k];
        acc[k] = 0.f;
    }
    int s0 = off[n], s1 = off[n + 1];
    for (int pos = s0 + sub; pos < s1; pos += 8) {
        int src = srcSorted[pos];
        float4 pa = *reinterpret_cast<const float4*>(p + src * PRP);
        float4 pb = *reinterpret_cast<const float4*>(p + src * PRP + 4);
        float h1[7];
        h1[0] = fmaxf(pa.x + qr[0], 0.f);
        h1[1] = fmaxf(pa.y + qr[1], 0.f);
        h1[2] = fmaxf(pa.z + qr[2], 0.f);
        h1[3] = fmaxf(pa.w + qr[3], 0.f);
        h1[4] = fmaxf(pb.x + qr[4], 0.f);
        h1[5] = fmaxf(pb.y + qr[5], 0.f);
        h1[6] = fmaxf(pb.z + qr[6], 0.f);
#pragma unroll
        for (int j = 0; j < 7; ++j) {
            float v = b2r[j];
#pragma unroll
            for (int k = 0; k < 7; ++k) v = fmaf(h1[k], w2r[k * 7 + j], v);
            acc[j] += fmaxf(v, 0.f);
        }
    }
#pragma unroll
    for (int j = 0; j < 7; ++j) {
        acc[j] += __shfl_down(acc[j], 4);
        acc[j] += __shfl_down(acc[j], 2);
        acc[j] += __shfl_down(acc[j], 1);
    }
    if (sub == 0) {
#pragma unroll
        for (int j = 0; j < 7; ++j) {
            H[n * PRP + j] = acc[j];
            if (FIRST) Hsum[n * PRP + j] = acc[j];
            else       Hsum[n * PRP + j] += acc[j];
        }
    }
}

// ---------------- tiny per-node propagation of the projections ----------------

__global__ void k_small_pq(float* __restrict__ p, float* __restrict__ q,
                           const float* __restrict__ H, const float* __restrict__ Wsm,
                           const int* __restrict__ off) {
    int n = blockIdx.x * blockDim.x + threadIdx.x;
    if (n >= N_NODES) return;
    float h[7];
#pragma unroll
    for (int k = 0; k < 7; ++k) h[k] = H[n * PRP + k];
    float degf = (float)(off[n + 1] - off[n]);
#pragma unroll
    for (int j = 0; j < 7; ++j) {
        float vp = degf * Wsm[OFF_BP + j];
        float vq = degf * Wsm[OFF_BQ + j];
#pragma unroll
        for (int i = 0; i < 7; ++i) {
            vp = fmaf(h[i], Wsm[OFF_WPP + i * 7 + j], vp);
            vq = fmaf(h[i], Wsm[OFF_WQQ + i * 7 + j], vq);
        }
        p[n * PRP + j] += vp;
        q[n * PRP + j] += vq;
    }
}

__global__ void k_small_rs(float* __restrict__ r, float* __restrict__ s,
                           const float* __restrict__ Hsum, const float* __restrict__ Wsm,
                           const int* __restrict__ off) {
    int n = blockIdx.x * blockDim.x + threadIdx.x;
    if (n >= N_NODES) return;
    float h[7];
#pragma unroll
    for (int k = 0; k < 7; ++k) h[k] = Hsum[n * PRP + k];
    float deg3 = 3.f * (float)(off[n + 1] - off[n]);
#pragma unroll
    for (int j = 0; j < 9; ++j) {
        float vr = deg3 * Wsm[OFF_BR + j];
        float vs = deg3 * Wsm[OFF_BS + j];
#pragma unroll
        for (int i = 0; i < 7; ++i) {
            vr = fmaf(h[i], Wsm[OFF_WR + i * 9 + j], vr);
            vs = fmaf(h[i], Wsm[OFF_WS + i * 9 + j], vs);
        }
        r[n * PG + j] += vr;
        s[n * PG + j] += vs;
    }
}

// ---------------- final pair scorer ----------------

__global__ void k_pair(const int* __restrict__ lab, const float* __restrict__ r,
                       const float* __restrict__ s, const float* __restrict__ w2,
                       const float* __restrict__ b1, const float* __restrict__ b2,
                       const float* __restrict__ w3, const float* __restrict__ b3,
                       float* __restrict__ out) {
    int b = blockIdx.x * blockDim.x + threadIdx.x;
    if (b >= B_PAIRS) return;
    int a0 = lab[2 * b];
    int a1 = lab[2 * b + 1];
    const float4* ra = reinterpret_cast<const float4*>(r + a0 * PG);
    const float4* sa = reinterpret_cast<const float4*>(s + a1 * PG);
    float4 r0 = ra[0], r1 = ra[1];
    float4 s0 = sa[0], s1 = sa[1];
    float rv[9] = {r0.x, r0.y, r0.z, r0.w, r1.x, r1.y, r1.z, r1.w, r[a0 * PG + 8]};
    float sv[9] = {s0.x, s0.y, s0.z, s0.w, s1.x, s1.y, s1.z, s1.w, s[a1 * PG + 8]};
    float g1[9];
#pragma unroll
    for (int k = 0; k < 9; ++k) g1[k] = fmaxf(rv[k] + sv[k] + b1[k], 0.f);
    float logit = b3[0];
#pragma unroll
    for (int j = 0; j < 9; ++j) {
        float v = b2[j];
#pragma unroll
        for (int k = 0; k < 9; ++k) v = fmaf(g1[k], w2[k * 9 + j], v);
        logit = fmaf(fmaxf(v, 0.f), w3[j], logit);
    }
    out[b] = 1.f / (1.f + expf(-logit));
}

// ---------------- launch ----------------

extern "C" void kernel_launch(void* const* d_in, const int* in_sizes, int n_in,
                              void* d_out, int out_size, void* d_ws, size_t ws_size,
                              hipStream_t stream) {
    const float* score = (const float*)d_in[0];
    const int2*  edges = (const int2*)d_in[1];
    const int*   lab   = (const int*)d_in[2];
    const float* rp_w1 = (const float*)d_in[3];
    const float* rp_b1 = (const float*)d_in[4];
    const float* rp_w2 = (const float*)d_in[5];
    const float* rp_b2 = (const float*)d_in[6];
    const float* rp_w3 = (const float*)d_in[7];
    const float* rp_b3 = (const float*)d_in[8];
    const float* g_w1  = (const float*)d_in[9];
    const float* g_b1  = (const float*)d_in[10];
    const float* g_w2  = (const float*)d_in[11];
    const float* g_b2  = (const float*)d_in[12];
    const float* g_w3  = (const float*)d_in[13];
    const float* g_b3  = (const float*)d_in[14];
    float* out = (float*)d_out;

    // ---- workspace layout ----
    float* ws   = (float*)d_ws;
    float* p    = ws;                       // N*8
    float* q    = p + N_NODES * PRP;        // N*8
    float* H    = q + N_NODES * PRP;        // N*8
    float* Hs   = H + N_NODES * PRP;        // N*8
    float* r    = Hs + N_NODES * PRP;       // N*16
    float* s    = r + N_NODES * PG;         // N*16
    float* Wbig = s + N_NODES * PG;         // 4096
    float* Wsm  = Wbig + 4096;              // 256
    // int region (starts 8B-aligned: 3,204,352 floats from base)
    int2* bucketed = (int2*)(Wsm + 256);    // E int2
    int* srcSorted = (int*)(bucketed + E_EDGES);  // E
    int* histT     = srcSorted + E_EDGES;   // HSZ
    int* histTs    = histT + HSZ;           // HSZ
    int* part      = histTs + HSZ;          // HSZ
    int* bsum      = part + HSZ;            // 256
    int* boff      = bsum + 256;            // 256
    int* off       = boff + 256;            // N+1

    const int SCAN1_B = (HSZ + 255) / 256;  // 151

    // ---- two-level bucket sort of edges by dst (no global atomics) ----
    k_histA<<<NCHUNK, 256, 0, stream>>>(edges, histT);
    k_scan1<<<SCAN1_B, 256, 0, stream>>>(histT, part, bsum, HSZ);
    k_scan2<<<1, 256, 0, stream>>>(bsum, boff, SCAN1_B);
    k_scan3<<<SCAN1_B, 256, 0, stream>>>(part, boff, histTs, HSZ);
    k_scatterA<<<NCHUNK, 256, 0, stream>>>(edges, histTs, bucketed);
    k_passB<<<NBUCKET, 256, 0, stream>>>(bucketed, histTs, srcSorted, off);

    // ---- pack weights ----
    k_wpack<<<17, 256, 0, stream>>>(rp_w1, g_w1, rp_w3, rp_b3, Wbig, Wsm);

    // ---- one fused projection of the ORIGINAL score ----
    const int PROJ_BLOCKS = 1280;
    k_proj_fused<<<PROJ_BLOCKS, 256, 0, stream>>>(score, Wbig, p, q, r, s, PROJ_BLOCKS * 4);

    // ---- 3 rounds in the tiny projected space ----
    const int EG = (8 * N_NODES + 255) / 256;
    const int NG = (N_NODES + 255) / 256;
    k_edge_node<true><<<EG, 256, 0, stream>>>(srcSorted, off, p, q, rp_w2, rp_b1, rp_b2, H, Hs);
    k_small_pq<<<NG, 256, 0, stream>>>(p, q, H, Wsm, off);
    k_edge_node<false><<<EG, 256, 0, stream>>>(srcSorted, off, p, q, rp_w2, rp_b1, rp_b2, H, Hs);
    k_small_pq<<<NG, 256, 0, stream>>>(p, q, H, Wsm, off);
    k_edge_node<false><<<EG, 256, 0, stream>>>(srcSorted, off, p, q, rp_w2, rp_b1, rp_b2, H, Hs);
    k_small_rs<<<NG, 256, 0, stream>>>(r, s, Hs, Wsm, off);

    // ---- final pair scorer ----
    k_pair<<<(B_PAIRS + 255) / 256, 256, 0, stream>>>(lab, r, s, g_w2, g_b1, g_b2, g_w3, g_b3, out);
}